// Round 1
// baseline (163.078 us; speedup 1.0000x reference)
//
#include <hip/hip_runtime.h>
#include <cstdint>
#include <cstddef>
#include <math.h>

#define S_LEN  256
#define BATCH  32
#define HID    256
#define EMB    256
#define TSTEPS 10
#define NW     8      // waves per block (512 threads)

// ---------------------------------------------------------------------------
// Single fused kernel. One block per batch element, 8 waves per block.
//
// Silence proof (Cauchy-Schwarz, PER BLOCK): block b only ever consumes
// tokens text[:, b], so max||emb[tok]||^2 over *its own* 256 tokens suffices:
//   max X1 <= max(b1) + maxE*maxW  <  thr1*(1-leak1)  =>  layer 1 never
// spikes for this batch element => layer-2 input is exactly b2 => (checked)
// layer 2 never spikes => acc accumulates exactly b3 per step. No global
// reduction => no workspace, no extra kernels, no inter-kernel sync.
// If any condition is unprovable, wave 0 runs the exact bit-level simulation
// (ballot spike masks, active-column sums) — correct for arbitrary data.
// ---------------------------------------------------------------------------

__device__ __forceinline__ float wave_sum(float s) {
#pragma unroll
    for (int off = 1; off < 64; off <<= 1)
        s += __shfl_xor(s, off, 64);
    return s;
}

__device__ __forceinline__ float wave_max(float s) {
#pragma unroll
    for (int off = 1; off < 64; off <<= 1)
        s = fmaxf(s, __shfl_xor(s, off, 64));
    return s;
}

__global__ __launch_bounds__(512) void snn_fused_kernel(
    const int* __restrict__ text, const float* __restrict__ emb,
    const float* __restrict__ W1, const float* __restrict__ b1,
    const float* __restrict__ W2, const float* __restrict__ b2,
    const float* __restrict__ W3, const float* __restrict__ b3,
    const float* __restrict__ thr1p, const float* __restrict__ leak1p,
    const float* __restrict__ thr2p, const float* __restrict__ leak2p,
    const float* __restrict__ Wa1, const float* __restrict__ ba1,
    const float* __restrict__ Wa2, const float* __restrict__ ba2,
    float* __restrict__ out)
{
    const int b   = blockIdx.x;   // batch element
    const int tid = threadIdx.x;
    const int l   = tid & 63;     // lane
    const int w   = tid >> 6;     // wave 0..7

    const float thr1  = thr1p[0],  thr2  = thr2p[0];
    const float leak1 = leak1p[0], leak2 = leak2p[0];

    __shared__ __align__(16) float hsh[HID];   // h = acc / B
    __shared__ float rsh[HID];                 // relu(h@Wa1^T + ba1)
    __shared__ int   stok[S_LEN];              // this block's token ids
    __shared__ float redW[NW], redE[NW], redB[NW];
    __shared__ int   redF[NW];
    __shared__ float sW2max, sE2max, sB1max;
    __shared__ int   sflags;                   // bit0 = bad, bit1 = b3 nonzero

    // ---- phase 0: stage tokens + per-thread bias loads (threads 0..255) ----
    float b1t = 0.f, b2t = 0.f, b3t = 0.f;
    if (tid < HID) {
        b1t = b1[tid];
        b2t = b2[tid];
        b3t = b3[tid];
        stok[tid] = text[tid * BATCH + b];
    }
    __syncthreads();

    // ---- phase 1: max ||W1 row||^2 — coalesced row reads, butterfly sum ----
    float mW = 0.f;
#pragma unroll 4
    for (int r = w; r < HID; r += NW) {
        const float4 v = ((const float4*)(W1 + (size_t)r * EMB))[l];
        const float s = wave_sum(v.x * v.x + v.y * v.y + v.z * v.z + v.w * v.w);
        mW = fmaxf(mW, isnan(s) ? INFINITY : s);
    }

    // ---- phase 2: max ||emb[tok]||^2 over THIS block's tokens ----
    // tok==0 contributes 0 (padding row zeroed in the reference).
    float mE = 0.f;
#pragma unroll 4
    for (int s0 = w; s0 < S_LEN; s0 += NW) {
        const int tok = stok[s0];
        const float4 v = ((const float4*)(emb + (size_t)tok * EMB))[l];
        const float s = wave_sum(v.x * v.x + v.y * v.y + v.z * v.z + v.w * v.w);
        if (tok != 0) mE = fmaxf(mE, isnan(s) ? INFINITY : s);
    }

    // ---- phase 3: scalar checks (b1 max, b2 silence condition, b3!=0) ----
    const float c2 = thr2 * (1.0f - leak2) - 1e-4f * thr2 - 1e-6f;
    bool badt = false, b3nzt = false;
    float mB1 = -INFINITY;
    if (tid < HID) {
        mB1   = isnan(b1t) ? INFINITY : b1t;
        badt  = !(b2t < c2);                      // catches NaN too
        b3nzt = (b3t != 0.0f) || isnan(b3t);
    }
    mB1 = wave_max(mB1);
    const unsigned long long mbad = __ballot(badt);
    const unsigned long long mnz  = __ballot(b3nzt);
    if (l == 0) {
        redW[w] = mW;
        redE[w] = mE;
        redB[w] = mB1;
        redF[w] = (mbad ? 1 : 0) | (mnz ? 2 : 0);
    }
    __syncthreads();
    if (tid == 0) {
        float a = 0.f, e = 0.f, bb = -INFINITY;
        int f = 0;
        for (int i = 0; i < NW; ++i) {
            a  = fmaxf(a,  redW[i]);
            e  = fmaxf(e,  redE[i]);
            bb = fmaxf(bb, redB[i]);
            f |= redF[i];
        }
        if (!(leak1 >= 0.0f && leak1 < 1.0f &&
              leak2 >= 0.0f && leak2 < 1.0f &&
              thr1 > 0.0f && thr2 > 0.0f)) f |= 1;
        sW2max = a; sE2max = e; sB1max = bb; sflags = f;
    }
    __syncthreads();

    const int   flags  = sflags;
    const float bound  = sqrtf(sE2max * sW2max) * 1.0001f + sB1max + 1e-6f;
    const float c1     = thr1 * (1.0f - leak1) - 1e-4f * thr1 - 1e-6f;
    const bool  silent = ((flags & 1) == 0) && (bound < c1);
    const bool  b3anz  = (flags & 2) != 0;

    // ---- phase 4: produce h = acc / B into LDS ----
    if (silent) {
        if (tid < HID) {
            float a = 0.f;
            if (b3anz) {
                // replicate the reference's sequential rounding order
                for (int st = 0; st < S_LEN * TSTEPS; ++st) a += b3t;
            }
            hsh[tid] = a * (1.0f / (float)BATCH);
        }
    } else if (w == 0) {
        // -------- exact in-kernel fallback (wave 0, lane l = neurons l+64k) --
        float b1f[4], b2f[4], b3f[4];
#pragma unroll
        for (int k = 0; k < 4; ++k) {
            b1f[k] = b1[l + 64 * k];
            b2f[k] = b2[l + 64 * k];
            b3f[k] = b3[l + 64 * k];
        }
        float m1[4] = {0.f, 0.f, 0.f, 0.f};
        float m2[4] = {0.f, 0.f, 0.f, 0.f};
        float acc[4] = {0.f, 0.f, 0.f, 0.f};

        for (int s = 0; s < S_LEN; ++s) {
            float X1c[4];
            {
                int tok = stok[s];
                tok = __builtin_amdgcn_readfirstlane(tok);
                const float4* __restrict__ xr = (const float4*)(emb + (size_t)tok * EMB);
                const float sc = (tok == 0) ? 0.0f : 1.0f;
#pragma unroll
                for (int k = 0; k < 4; ++k) {
                    const float4* __restrict__ wr =
                        (const float4*)(W1 + (size_t)(l + 64 * k) * EMB);
                    float a = 0.f;
                    for (int j4 = 0; j4 < EMB / 4; ++j4) {
                        float4 wv = wr[j4];
                        float4 xv = xr[j4];
                        a += wv.x * xv.x + wv.y * xv.y + wv.z * xv.z + wv.w * xv.w;
                    }
                    X1c[k] = b1f[k] + sc * a;
                }
            }

#pragma unroll
            for (int t = 0; t < TSTEPS; ++t) {
                unsigned long long msk[4];

#pragma unroll
                for (int k = 0; k < 4; ++k) {
                    m1[k] = fmaf(m1[k], leak1, X1c[k]);
                    const bool sp = m1[k] > thr1;
                    msk[k] = __ballot(sp);
                    m1[k] -= sp ? thr1 : 0.f;
                }

                float d2[4] = {b2f[0], b2f[1], b2f[2], b2f[3]};
                if (msk[0] | msk[1] | msk[2] | msk[3]) {
#pragma unroll
                    for (int k2 = 0; k2 < 4; ++k2) {
                        unsigned long long m = msk[k2];
                        while (m) {
                            const int j = (k2 << 6) + __builtin_ctzll(m);
                            m &= m - 1;
#pragma unroll
                            for (int k = 0; k < 4; ++k)
                                d2[k] += W2[(size_t)(l + 64 * k) * HID + j];
                        }
                    }
                }

#pragma unroll
                for (int k = 0; k < 4; ++k) {
                    m2[k] = fmaf(m2[k], leak2, d2[k]);
                    const bool sp = m2[k] > thr2;
                    msk[k] = __ballot(sp);
                    m2[k] -= sp ? thr2 : 0.f;
                }

                float d3[4] = {b3f[0], b3f[1], b3f[2], b3f[3]};
                if (msk[0] | msk[1] | msk[2] | msk[3]) {
#pragma unroll
                    for (int k2 = 0; k2 < 4; ++k2) {
                        unsigned long long m = msk[k2];
                        while (m) {
                            const int j = (k2 << 6) + __builtin_ctzll(m);
                            m &= m - 1;
#pragma unroll
                            for (int k = 0; k < 4; ++k)
                                d3[k] += W3[(size_t)(l + 64 * k) * HID + j];
                        }
                    }
                }
#pragma unroll
                for (int k = 0; k < 4; ++k) acc[k] += d3[k];
            }
        }
#pragma unroll
        for (int k = 0; k < 4; ++k)
            hsh[l + 64 * k] = acc[k] * (1.0f / (float)BATCH);
    }
    __syncthreads();

    // ---- phase 5: epilogue — relu(h@Wa1^T + ba1) @ Wa2^T + ba2 ----
    const float4 hv = ((const float4*)hsh)[l];
#pragma unroll 4
    for (int r = w; r < HID; r += NW) {
        const float4 wv = ((const float4*)(Wa1 + (size_t)r * HID))[l];
        const float a = wave_sum(wv.x * hv.x + wv.y * hv.y +
                                 wv.z * hv.z + wv.w * hv.w);
        if (l == 0) rsh[r] = fmaxf(a + ba1[r], 0.0f);
    }
    __syncthreads();

    if (w == 0) {
        float p = 0.f;
#pragma unroll
        for (int k = 0; k < 4; ++k)
            p += Wa2[l + 64 * k] * rsh[l + 64 * k];
        p = wave_sum(p);
        if (l == 0) out[b] = p + ba2[0];
    }
}

// ---------------------------------------------------------------------------
extern "C" void kernel_launch(void* const* d_in, const int* in_sizes, int n_in,
                              void* d_out, int out_size, void* d_ws, size_t ws_size,
                              hipStream_t stream)
{
    const int*   text   = (const int*)  d_in[0];
    // d_in[1] = text_lengths: unused by the reference
    const float* emb    = (const float*)d_in[2];
    const float* W1     = (const float*)d_in[3];
    const float* b1     = (const float*)d_in[4];
    const float* thr1   = (const float*)d_in[5];
    const float* leak1  = (const float*)d_in[6];
    const float* W2     = (const float*)d_in[7];
    const float* b2     = (const float*)d_in[8];
    const float* thr2   = (const float*)d_in[9];
    const float* leak2  = (const float*)d_in[10];
    const float* W3     = (const float*)d_in[11];
    const float* b3     = (const float*)d_in[12];
    const float* Wa1    = (const float*)d_in[13];
    const float* ba1    = (const float*)d_in[14];
    const float* Wa2    = (const float*)d_in[15];
    const float* ba2    = (const float*)d_in[16];
    float*       out    = (float*)d_out;

    (void)d_ws; (void)ws_size;   // no workspace needed: proof is per-block

    snn_fused_kernel<<<BATCH, 512, 0, stream>>>(
        text, emb, W1, b1, W2, b2, W3, b3,
        thr1, leak1, thr2, leak2,
        Wa1, ba1, Wa2, ba2, out);
}

// Round 2
// 137.666 us; speedup vs baseline: 1.1846x; 1.1846x over previous
//
#include <hip/hip_runtime.h>
#include <cstdint>
#include <cstddef>
#include <math.h>

#define S_LEN  256
#define BATCH  32
#define HID    256
#define EMB    256
#define TSTEPS 10

// Scratch (ints): [0..31]  per-batch max ||emb[tok]||^2 (float bits, atomicMax)
//                 [32]     max ||W1 row||^2            (float bits, atomicMax)
//                 [33]     max b1                      (float, plain store)
//                 [34]     flags: bit0=bad params/b2, bit1=b3 nonzero
// All values fed to atomicMax are >= 0, so int-bit compare == float compare.
// hipMemsetAsync zeroes 256 B before K1.

// ---------------------------------------------------------------------------
// Kernel 1: whole-chip gather + stats.
//   Blocks 0..255 : batch b = g>>3, tokens (g&7)*32 .. +31. 8 threads/token,
//                   each reads 128 B contiguous (8 float4) -> one vmem instr
//                   per wave hits 64 distinct cache lines (max MLP), and every
//                   line is fully consumed. Butterfly-reduce within 8-lane
//                   groups, wave max, one atomicMax per wave.
//   Blocks 256..263: same shape over W1's 256 rows -> scratch[32].
//                   Block 256 additionally does the scalar checks.
// ---------------------------------------------------------------------------
__global__ __launch_bounds__(256) void gather_stats_kernel(
    const int* __restrict__ text, const float* __restrict__ emb,
    const float* __restrict__ W1, const float* __restrict__ b1,
    const float* __restrict__ b2, const float* __restrict__ b3,
    const float* __restrict__ thr1p, const float* __restrict__ leak1p,
    const float* __restrict__ thr2p, const float* __restrict__ leak2p,
    int* __restrict__ scratch)
{
    const int g   = blockIdx.x;
    const int tid = threadIdx.x;
    const int p   = tid & 7;        // part of row (128 B each)

    if (g < 256) {
        const int b    = g >> 3;
        const int t0   = (g & 7) * 32;
        const int trow = tid >> 3;                       // 0..31
        const int tok  = text[(t0 + trow) * BATCH + b];
        const float4* __restrict__ r =
            (const float4*)(emb + (size_t)tok * EMB) + p * 8;
        float s = 0.f;
#pragma unroll
        for (int j = 0; j < 8; ++j) {
            const float4 v = r[j];
            s += v.x * v.x + v.y * v.y + v.z * v.z + v.w * v.w;
        }
#pragma unroll
        for (int off = 1; off < 8; off <<= 1) s += __shfl_xor(s, off, 64);
        s = isnan(s) ? INFINITY : s;
        if (tok == 0) s = 0.f;                           // padding row zeroed in ref
#pragma unroll
        for (int off = 8; off < 64; off <<= 1) s = fmaxf(s, __shfl_xor(s, off, 64));
        if ((tid & 63) == 0) atomicMax(scratch + b, __float_as_int(s));
        return;
    }

    // ---- stats blocks ----
    const int q   = g - 256;                             // 0..7
    const int row = q * 32 + (tid >> 3);
    const float4* __restrict__ r = (const float4*)(W1 + (size_t)row * EMB) + p * 8;
    float s = 0.f;
#pragma unroll
    for (int j = 0; j < 8; ++j) {
        const float4 v = r[j];
        s += v.x * v.x + v.y * v.y + v.z * v.z + v.w * v.w;
    }
#pragma unroll
    for (int off = 1; off < 8; off <<= 1) s += __shfl_xor(s, off, 64);
    s = isnan(s) ? INFINITY : s;
#pragma unroll
    for (int off = 8; off < 64; off <<= 1) s = fmaxf(s, __shfl_xor(s, off, 64));
    if ((tid & 63) == 0) atomicMax(scratch + 32, __float_as_int(s));

    if (q == 0) {
        __shared__ float redB[256];
        __shared__ int   sflags;
        const float thr2  = thr2p[0], leak2 = leak2p[0];
        const float c2    = thr2 * (1.0f - leak2) - 1e-4f * thr2 - 1e-6f;
        const float b1i   = b1[tid];
        const float b2i   = b2[tid];
        const float b3i   = b3[tid];
        redB[tid] = isnan(b1i) ? INFINITY : b1i;
        bool bad  = !(b2i < c2);                          // catches NaN too
        bool b3nz = (b3i != 0.0f) || isnan(b3i);
        if (tid == 0) {
            const float thr1 = thr1p[0], leak1 = leak1p[0];
            bad |= !(leak1 >= 0.0f && leak1 < 1.0f &&
                     leak2 >= 0.0f && leak2 < 1.0f &&
                     thr1 > 0.0f && thr2 > 0.0f);
            sflags = 0;
        }
        __syncthreads();
        const unsigned long long mb = __ballot(bad);
        const unsigned long long m3 = __ballot(b3nz);
        if ((tid & 63) == 0) {
            int f = (mb ? 1 : 0) | (m3 ? 2 : 0);
            if (f) atomicOr(&sflags, f);
        }
        __syncthreads();
        for (int st = 128; st > 0; st >>= 1) {
            if (tid < st) redB[tid] = fmaxf(redB[tid], redB[tid + st]);
            __syncthreads();
        }
        if (tid == 0) {
            ((float*)scratch)[33] = redB[0];
            scratch[34]           = sflags;
        }
    }
}

// ---------------------------------------------------------------------------
// Kernel 2: decide + finalize. One block per batch element, 8 waves.
// Silence proof (Cauchy-Schwarz, per batch element): max X1 <= max(b1) +
// maxE*maxW < thr1*(1-leak1) => layer 1 never spikes => layer-2 input is
// exactly b2 => (checked) layer 2 never spikes => acc accumulates exactly
// b3 per step. If unprovable, wave 0 runs the exact bit-level simulation.
// ---------------------------------------------------------------------------
__device__ __forceinline__ float wave_sum(float s) {
#pragma unroll
    for (int off = 1; off < 64; off <<= 1) s += __shfl_xor(s, off, 64);
    return s;
}

__global__ __launch_bounds__(512) void snn_final_kernel(
    const int* __restrict__ text, const float* __restrict__ emb,
    const float* __restrict__ W1, const float* __restrict__ b1,
    const float* __restrict__ W2, const float* __restrict__ b2,
    const float* __restrict__ W3, const float* __restrict__ b3,
    const float* __restrict__ thr1p, const float* __restrict__ leak1p,
    const float* __restrict__ thr2p, const float* __restrict__ leak2p,
    const float* __restrict__ Wa1, const float* __restrict__ ba1,
    const float* __restrict__ Wa2, const float* __restrict__ ba2,
    const int* __restrict__ scratch, const int forceExact,
    float* __restrict__ out)
{
    const int b   = blockIdx.x;
    const int tid = threadIdx.x;
    const int l   = tid & 63;
    const int w   = tid >> 6;

    const float thr1  = thr1p[0],  thr2  = thr2p[0];
    const float leak1 = leak1p[0], leak2 = leak2p[0];

    __shared__ __align__(16) float hsh[HID];
    __shared__ float rsh[HID];
    __shared__ int   stok[S_LEN];          // needed only by the exact fallback

    if (tid < S_LEN) stok[tid] = text[tid * BATCH + b];

    bool silent = false;
    bool b3anz  = true;
    if (!forceExact) {
        const float maxE2 = __int_as_float(scratch[b]);
        const float maxW2 = __int_as_float(scratch[32]);
        const float maxb1 = ((const float*)scratch)[33];
        const int   flags = scratch[34];
        const float bound = sqrtf(maxE2 * maxW2) * 1.0001f + maxb1 + 1e-6f;
        const float c1    = thr1 * (1.0f - leak1) - 1e-4f * thr1 - 1e-6f;
        silent = ((flags & 1) == 0) && (bound < c1);
        b3anz  = (flags & 2) != 0;
    }
    __syncthreads();

    if (silent) {
        if (tid < HID) {
            float a = 0.f;
            if (b3anz) {
                const float b3t = b3[tid];
                // replicate the reference's sequential rounding order
                for (int st = 0; st < S_LEN * TSTEPS; ++st) a += b3t;
            }
            hsh[tid] = a * (1.0f / (float)BATCH);
        }
    } else if (w == 0) {
        // -------- exact in-kernel fallback (wave 0, lane l = neurons l+64k) --
        float b1f[4], b2f[4], b3f[4];
#pragma unroll
        for (int k = 0; k < 4; ++k) {
            b1f[k] = b1[l + 64 * k];
            b2f[k] = b2[l + 64 * k];
            b3f[k] = b3[l + 64 * k];
        }
        float m1[4]  = {0.f, 0.f, 0.f, 0.f};
        float m2[4]  = {0.f, 0.f, 0.f, 0.f};
        float acc[4] = {0.f, 0.f, 0.f, 0.f};

        for (int s = 0; s < S_LEN; ++s) {
            float X1c[4];
            {
                int tok = stok[s];
                tok = __builtin_amdgcn_readfirstlane(tok);
                const float4* __restrict__ xr = (const float4*)(emb + (size_t)tok * EMB);
                const float sc = (tok == 0) ? 0.0f : 1.0f;
#pragma unroll
                for (int k = 0; k < 4; ++k) {
                    const float4* __restrict__ wr =
                        (const float4*)(W1 + (size_t)(l + 64 * k) * EMB);
                    float a = 0.f;
                    for (int j4 = 0; j4 < EMB / 4; ++j4) {
                        float4 wv = wr[j4];
                        float4 xv = xr[j4];
                        a += wv.x * xv.x + wv.y * xv.y + wv.z * xv.z + wv.w * xv.w;
                    }
                    X1c[k] = b1f[k] + sc * a;
                }
            }

#pragma unroll
            for (int t = 0; t < TSTEPS; ++t) {
                unsigned long long msk[4];

#pragma unroll
                for (int k = 0; k < 4; ++k) {
                    m1[k] = fmaf(m1[k], leak1, X1c[k]);
                    const bool sp = m1[k] > thr1;
                    msk[k] = __ballot(sp);
                    m1[k] -= sp ? thr1 : 0.f;
                }

                float d2[4] = {b2f[0], b2f[1], b2f[2], b2f[3]};
                if (msk[0] | msk[1] | msk[2] | msk[3]) {
#pragma unroll
                    for (int k2 = 0; k2 < 4; ++k2) {
                        unsigned long long m = msk[k2];
                        while (m) {
                            const int j = (k2 << 6) + __builtin_ctzll(m);
                            m &= m - 1;
#pragma unroll
                            for (int k = 0; k < 4; ++k)
                                d2[k] += W2[(size_t)(l + 64 * k) * HID + j];
                        }
                    }
                }

#pragma unroll
                for (int k = 0; k < 4; ++k) {
                    m2[k] = fmaf(m2[k], leak2, d2[k]);
                    const bool sp = m2[k] > thr2;
                    msk[k] = __ballot(sp);
                    m2[k] -= sp ? thr2 : 0.f;
                }

                float d3[4] = {b3f[0], b3f[1], b3f[2], b3f[3]};
                if (msk[0] | msk[1] | msk[2] | msk[3]) {
#pragma unroll
                    for (int k2 = 0; k2 < 4; ++k2) {
                        unsigned long long m = msk[k2];
                        while (m) {
                            const int j = (k2 << 6) + __builtin_ctzll(m);
                            m &= m - 1;
#pragma unroll
                            for (int k = 0; k < 4; ++k)
                                d3[k] += W3[(size_t)(l + 64 * k) * HID + j];
                        }
                    }
                }
#pragma unroll
                for (int k = 0; k < 4; ++k) acc[k] += d3[k];
            }
        }
#pragma unroll
        for (int k = 0; k < 4; ++k)
            hsh[l + 64 * k] = acc[k] * (1.0f / (float)BATCH);
    }
    __syncthreads();

    // ---- epilogue: relu(h@Wa1^T + ba1) @ Wa2^T + ba2 ----
    const float4 hv = ((const float4*)hsh)[l];
#pragma unroll 4
    for (int r = w; r < HID; r += 8) {
        const float4 wv = ((const float4*)(Wa1 + (size_t)r * HID))[l];
        const float a = wave_sum(wv.x * hv.x + wv.y * hv.y +
                                 wv.z * hv.z + wv.w * hv.w);
        if (l == 0) rsh[r] = fmaxf(a + ba1[r], 0.0f);
    }
    __syncthreads();

    if (w == 0) {
        float p = 0.f;
#pragma unroll
        for (int k = 0; k < 4; ++k)
            p += Wa2[l + 64 * k] * rsh[l + 64 * k];
        p = wave_sum(p);
        if (l == 0) out[b] = p + ba2[0];
    }
}

// ---------------------------------------------------------------------------
extern "C" void kernel_launch(void* const* d_in, const int* in_sizes, int n_in,
                              void* d_out, int out_size, void* d_ws, size_t ws_size,
                              hipStream_t stream)
{
    const int*   text   = (const int*)  d_in[0];
    // d_in[1] = text_lengths: unused by the reference
    const float* emb    = (const float*)d_in[2];
    const float* W1     = (const float*)d_in[3];
    const float* b1     = (const float*)d_in[4];
    const float* thr1   = (const float*)d_in[5];
    const float* leak1  = (const float*)d_in[6];
    const float* W2     = (const float*)d_in[7];
    const float* b2     = (const float*)d_in[8];
    const float* thr2   = (const float*)d_in[9];
    const float* leak2  = (const float*)d_in[10];
    const float* W3     = (const float*)d_in[11];
    const float* b3     = (const float*)d_in[12];
    const float* Wa1    = (const float*)d_in[13];
    const float* ba1    = (const float*)d_in[14];
    const float* Wa2    = (const float*)d_in[15];
    const float* ba2    = (const float*)d_in[16];
    float*       out    = (float*)d_out;

    int* scratch = (int*)d_ws;
    const int have_ws = (ws_size >= 256) ? 1 : 0;

    if (have_ws) {
        hipMemsetAsync(scratch, 0, 256, stream);
        gather_stats_kernel<<<264, 256, 0, stream>>>(
            text, emb, W1, b1, b2, b3, thr1, leak1, thr2, leak2, scratch);
    }
    snn_final_kernel<<<BATCH, 512, 0, stream>>>(
        text, emb, W1, b1, W2, b2, W3, b3,
        thr1, leak1, thr2, leak2,
        Wa1, ba1, Wa2, ba2,
        scratch, have_ws ? 0 : 1, out);
}

// Round 3
// 119.682 us; speedup vs baseline: 1.3626x; 1.1503x over previous
//
#include <hip/hip_runtime.h>
#include <cstdint>
#include <cstddef>
#include <math.h>

#define S_LEN  256
#define BATCH  32
#define HID    256
#define EMB    256
#define TSTEPS 10

// Scratch (no init required — every slot K2 reads is plain-stored by K1):
//   float [0..255]   : gather block g -> max ||emb[tok]||^2 over its 32 tokens
//                      (batch b = g>>3, chunk = g&7)
//   float [256..263] : W1 block q -> max ||W1 row||^2 over its 32 rows
//   float [264]      : max b1
//   int   [265]      : flags  bit0 = bad params / b2 condition, bit1 = b3 nonzero
//   int   [266..273] : Wa1 block q -> 1 if any non-finite entry in its 32 rows
#define SCR_W1   256
#define SCR_B1   264
#define SCR_FLG  265
#define SCR_WA1  266

// ---------------------------------------------------------------------------
// Kernel 1: whole-chip stats. 272 blocks x 256 threads.
//   g in [0,256)   : emb-row norms for batch g>>3, tokens (g&7)*32..+31.
//                    8 threads/token, 128 B contiguous each -> one vmem instr
//                    per wave hits 64 distinct lines, every line fully used.
//   g in [256,264) : ||W1 row||^2 (block 256 also does the scalar checks).
//   g in [264,272) : Wa1 finiteness scan (enables the 0 @ Wa1 == 0 shortcut).
// Per-block results go to private slots -> no atomics, no memset dispatch.
// ---------------------------------------------------------------------------
__global__ __launch_bounds__(256) void gather_stats_kernel(
    const int* __restrict__ text, const float* __restrict__ emb,
    const float* __restrict__ W1, const float* __restrict__ b1,
    const float* __restrict__ b2, const float* __restrict__ b3,
    const float* __restrict__ Wa1,
    const float* __restrict__ thr1p, const float* __restrict__ leak1p,
    const float* __restrict__ thr2p, const float* __restrict__ leak2p,
    int* __restrict__ scratch)
{
    const int g   = blockIdx.x;
    const int tid = threadIdx.x;
    const int p   = tid & 7;          // 128 B segment of the 1 KB row
    float* scrf = (float*)scratch;

    __shared__ float redw[4];

    if (g < 256) {
        const int b    = g >> 3;
        const int trow = tid >> 3;                        // 0..31
        const int tok  = text[((g & 7) * 32 + trow) * BATCH + b];
        const float4* __restrict__ r =
            (const float4*)(emb + (size_t)tok * EMB) + p * 8;
        float s = 0.f;
#pragma unroll
        for (int j = 0; j < 8; ++j) {
            const float4 v = r[j];
            s += v.x * v.x + v.y * v.y + v.z * v.z + v.w * v.w;
        }
#pragma unroll
        for (int off = 1; off < 8; off <<= 1) s += __shfl_xor(s, off, 64);
        s = isnan(s) ? INFINITY : s;
        if (tok == 0) s = 0.f;        // padding row zeroed in the reference
#pragma unroll
        for (int off = 8; off < 64; off <<= 1) s = fmaxf(s, __shfl_xor(s, off, 64));
        if ((tid & 63) == 0) redw[tid >> 6] = s;
        __syncthreads();
        if (tid == 0)
            scrf[g] = fmaxf(fmaxf(redw[0], redw[1]), fmaxf(redw[2], redw[3]));
        return;
    }

    if (g < 264) {
        // ---- W1 row norms ----
        const int q   = g - 256;
        const int row = q * 32 + (tid >> 3);
        const float4* __restrict__ r =
            (const float4*)(W1 + (size_t)row * EMB) + p * 8;
        float s = 0.f;
#pragma unroll
        for (int j = 0; j < 8; ++j) {
            const float4 v = r[j];
            s += v.x * v.x + v.y * v.y + v.z * v.z + v.w * v.w;
        }
#pragma unroll
        for (int off = 1; off < 8; off <<= 1) s += __shfl_xor(s, off, 64);
        s = isnan(s) ? INFINITY : s;
#pragma unroll
        for (int off = 8; off < 64; off <<= 1) s = fmaxf(s, __shfl_xor(s, off, 64));
        if ((tid & 63) == 0) redw[tid >> 6] = s;
        __syncthreads();
        if (tid == 0)
            scrf[g] = fmaxf(fmaxf(redw[0], redw[1]), fmaxf(redw[2], redw[3]));
        if (q != 0) return;

        // ---- block 256 only: scalar checks (b1 max, b2 silence, b3!=0) ----
        __shared__ float redB[256];
        __shared__ int   wf[4];
        const float thr2  = thr2p[0], leak2 = leak2p[0];
        const float c2    = thr2 * (1.0f - leak2) - 1e-4f * thr2 - 1e-6f;
        const float b1i   = b1[tid];
        const float b2i   = b2[tid];
        const float b3i   = b3[tid];
        redB[tid] = isnan(b1i) ? INFINITY : b1i;
        bool bad  = !(b2i < c2);                          // catches NaN too
        bool b3nz = (b3i != 0.0f) || isnan(b3i);
        if (tid == 0) {
            const float thr1 = thr1p[0], leak1 = leak1p[0];
            bad |= !(leak1 >= 0.0f && leak1 < 1.0f &&
                     leak2 >= 0.0f && leak2 < 1.0f &&
                     thr1 > 0.0f && thr2 > 0.0f);
        }
        const unsigned long long mb = __ballot(bad);
        const unsigned long long m3 = __ballot(b3nz);
        if ((tid & 63) == 0) wf[tid >> 6] = (mb ? 1 : 0) | (m3 ? 2 : 0);
        __syncthreads();
        for (int st = 128; st > 0; st >>= 1) {
            if (tid < st) redB[tid] = fmaxf(redB[tid], redB[tid + st]);
            __syncthreads();
        }
        if (tid == 0) {
            scrf[SCR_B1]     = redB[0];
            scratch[SCR_FLG] = wf[0] | wf[1] | wf[2] | wf[3];
        }
        return;
    }

    // ---- Wa1 finiteness scan, g in [264,272) ----
    {
        const int q   = g - 264;
        const int row = q * 32 + (tid >> 3);
        const float4* __restrict__ r =
            (const float4*)(Wa1 + (size_t)row * HID) + p * 8;
        bool nf = false;
#pragma unroll
        for (int j = 0; j < 8; ++j) {
            const float4 v = r[j];
            nf |= !isfinite(v.x) || !isfinite(v.y) ||
                  !isfinite(v.z) || !isfinite(v.w);
        }
        const unsigned long long m = __ballot(nf);
        __shared__ int wnf[4];
        if ((tid & 63) == 0) wnf[tid >> 6] = (m != 0ULL) ? 1 : 0;
        __syncthreads();
        if (tid == 0)
            scratch[SCR_WA1 + q] = wnf[0] | wnf[1] | wnf[2] | wnf[3];
    }
}

// ---------------------------------------------------------------------------
// Kernel 2: decide + finalize. One block per batch element, 8 waves.
// Silence proof (Cauchy-Schwarz, per batch element): max X1 <= max(b1) +
// maxE*maxW < thr1*(1-leak1) => layer 1 never spikes => layer-2 input is
// exactly b2 => (checked) layer 2 never spikes => acc accumulates exactly
// b3 per step. If additionally b3 == 0 and Wa1 is finite, h == +0 exactly
// and 0 @ Wa1^T == 0 exactly => out = relu(ba1) @ Wa2^T + ba2 directly.
// If the proof fails, wave 0 runs the exact bit-level simulation.
// ---------------------------------------------------------------------------
__device__ __forceinline__ float wave_sum(float s) {
#pragma unroll
    for (int off = 1; off < 64; off <<= 1) s += __shfl_xor(s, off, 64);
    return s;
}

__global__ __launch_bounds__(512) void snn_final_kernel(
    const int* __restrict__ text, const float* __restrict__ emb,
    const float* __restrict__ W1, const float* __restrict__ b1,
    const float* __restrict__ W2, const float* __restrict__ b2,
    const float* __restrict__ W3, const float* __restrict__ b3,
    const float* __restrict__ thr1p, const float* __restrict__ leak1p,
    const float* __restrict__ thr2p, const float* __restrict__ leak2p,
    const float* __restrict__ Wa1, const float* __restrict__ ba1,
    const float* __restrict__ Wa2, const float* __restrict__ ba2,
    const int* __restrict__ scratch, const int forceExact,
    float* __restrict__ out)
{
    const int b   = blockIdx.x;
    const int tid = threadIdx.x;
    const int l   = tid & 63;
    const int w   = tid >> 6;

    const float thr1  = thr1p[0],  thr2  = thr2p[0];
    const float leak1 = leak1p[0], leak2 = leak2p[0];

    bool silent = false;
    bool b3anz  = true;
    bool wa1bad = true;
    if (!forceExact) {
        const float* scrf = (const float*)scratch;
        float maxE2 = 0.f, maxW2 = 0.f;
        int   wnf   = 0;
#pragma unroll
        for (int i = 0; i < 8; ++i) {
            maxE2 = fmaxf(maxE2, scrf[b * 8 + i]);
            maxW2 = fmaxf(maxW2, scrf[SCR_W1 + i]);
            wnf  |= scratch[SCR_WA1 + i];
        }
        const float maxb1 = scrf[SCR_B1];
        const int   flags = scratch[SCR_FLG];
        const float bound = sqrtf(maxE2 * maxW2) * 1.0001f + maxb1 + 1e-6f;
        const float c1    = thr1 * (1.0f - leak1) - 1e-4f * thr1 - 1e-6f;
        silent = ((flags & 1) == 0) && (bound < c1);
        b3anz  = (flags & 2) != 0;
        wa1bad = (wnf != 0);
    }

    __shared__ __align__(16) float hsh[HID];
    __shared__ float rsh[HID];
    __shared__ int   stok[S_LEN];          // used only by the exact fallback

    if (silent && !b3anz && !wa1bad) {
        // ---- fast path: h == +0 exactly, Wa1 finite => h@Wa1^T == 0 ----
        if (w == 0) {
            float p = 0.f;
#pragma unroll
            for (int k = 0; k < 4; ++k) {
                const int i = l + 64 * k;
                p += Wa2[i] * fmaxf(ba1[i], 0.0f);
            }
            p = wave_sum(p);
            if (l == 0) out[b] = p + ba2[0];
        }
        return;                             // block-uniform
    }

    if (silent) {
        // layers silent but b3 != 0: acc = b3 added S*T times in the
        // reference's sequential rounding order.
        if (tid < HID) {
            const float b3t = b3[tid];
            float a = 0.f;
            for (int st = 0; st < S_LEN * TSTEPS; ++st) a += b3t;
            hsh[tid] = a * (1.0f / (float)BATCH);
        }
    } else if (w == 0) {
        // -------- exact in-kernel fallback (wave 0, lane l = neurons l+64k) --
        for (int i = l; i < S_LEN; i += 64) stok[i] = text[i * BATCH + b];

        float b1f[4], b2f[4], b3f[4];
#pragma unroll
        for (int k = 0; k < 4; ++k) {
            b1f[k] = b1[l + 64 * k];
            b2f[k] = b2[l + 64 * k];
            b3f[k] = b3[l + 64 * k];
        }
        float m1[4]  = {0.f, 0.f, 0.f, 0.f};
        float m2[4]  = {0.f, 0.f, 0.f, 0.f};
        float acc[4] = {0.f, 0.f, 0.f, 0.f};

        for (int s = 0; s < S_LEN; ++s) {
            float X1c[4];
            {
                int tok = stok[s];
                tok = __builtin_amdgcn_readfirstlane(tok);
                const float4* __restrict__ xr = (const float4*)(emb + (size_t)tok * EMB);
                const float sc = (tok == 0) ? 0.0f : 1.0f;
#pragma unroll
                for (int k = 0; k < 4; ++k) {
                    const float4* __restrict__ wr =
                        (const float4*)(W1 + (size_t)(l + 64 * k) * EMB);
                    float a = 0.f;
                    for (int j4 = 0; j4 < EMB / 4; ++j4) {
                        float4 wv = wr[j4];
                        float4 xv = xr[j4];
                        a += wv.x * xv.x + wv.y * xv.y + wv.z * xv.z + wv.w * xv.w;
                    }
                    X1c[k] = b1f[k] + sc * a;
                }
            }

#pragma unroll
            for (int t = 0; t < TSTEPS; ++t) {
                unsigned long long msk[4];

#pragma unroll
                for (int k = 0; k < 4; ++k) {
                    m1[k] = fmaf(m1[k], leak1, X1c[k]);
                    const bool sp = m1[k] > thr1;
                    msk[k] = __ballot(sp);
                    m1[k] -= sp ? thr1 : 0.f;
                }

                float d2[4] = {b2f[0], b2f[1], b2f[2], b2f[3]};
                if (msk[0] | msk[1] | msk[2] | msk[3]) {
#pragma unroll
                    for (int k2 = 0; k2 < 4; ++k2) {
                        unsigned long long m = msk[k2];
                        while (m) {
                            const int j = (k2 << 6) + __builtin_ctzll(m);
                            m &= m - 1;
#pragma unroll
                            for (int k = 0; k < 4; ++k)
                                d2[k] += W2[(size_t)(l + 64 * k) * HID + j];
                        }
                    }
                }

#pragma unroll
                for (int k = 0; k < 4; ++k) {
                    m2[k] = fmaf(m2[k], leak2, d2[k]);
                    const bool sp = m2[k] > thr2;
                    msk[k] = __ballot(sp);
                    m2[k] -= sp ? thr2 : 0.f;
                }

                float d3[4] = {b3f[0], b3f[1], b3f[2], b3f[3]};
                if (msk[0] | msk[1] | msk[2] | msk[3]) {
#pragma unroll
                    for (int k2 = 0; k2 < 4; ++k2) {
                        unsigned long long m = msk[k2];
                        while (m) {
                            const int j = (k2 << 6) + __builtin_ctzll(m);
                            m &= m - 1;
#pragma unroll
                            for (int k = 0; k < 4; ++k)
                                d3[k] += W3[(size_t)(l + 64 * k) * HID + j];
                        }
                    }
                }
#pragma unroll
                for (int k = 0; k < 4; ++k) acc[k] += d3[k];
            }
        }
#pragma unroll
        for (int k = 0; k < 4; ++k)
            hsh[l + 64 * k] = acc[k] * (1.0f / (float)BATCH);
    }
    __syncthreads();

    // ---- epilogue: relu(h@Wa1^T + ba1) @ Wa2^T + ba2 ----
    const float4 hv = ((const float4*)hsh)[l];
#pragma unroll 4
    for (int r = w; r < HID; r += 8) {
        const float4 wv = ((const float4*)(Wa1 + (size_t)r * HID))[l];
        const float a = wave_sum(wv.x * hv.x + wv.y * hv.y +
                                 wv.z * hv.z + wv.w * hv.w);
        if (l == 0) rsh[r] = fmaxf(a + ba1[r], 0.0f);
    }
    __syncthreads();

    if (w == 0) {
        float p = 0.f;
#pragma unroll
        for (int k = 0; k < 4; ++k)
            p += Wa2[l + 64 * k] * rsh[l + 64 * k];
        p = wave_sum(p);
        if (l == 0) out[b] = p + ba2[0];
    }
}

// ---------------------------------------------------------------------------
extern "C" void kernel_launch(void* const* d_in, const int* in_sizes, int n_in,
                              void* d_out, int out_size, void* d_ws, size_t ws_size,
                              hipStream_t stream)
{
    const int*   text   = (const int*)  d_in[0];
    // d_in[1] = text_lengths: unused by the reference
    const float* emb    = (const float*)d_in[2];
    const float* W1     = (const float*)d_in[3];
    const float* b1     = (const float*)d_in[4];
    const float* thr1   = (const float*)d_in[5];
    const float* leak1  = (const float*)d_in[6];
    const float* W2     = (const float*)d_in[7];
    const float* b2     = (const float*)d_in[8];
    const float* thr2   = (const float*)d_in[9];
    const float* leak2  = (const float*)d_in[10];
    const float* W3     = (const float*)d_in[11];
    const float* b3     = (const float*)d_in[12];
    const float* Wa1    = (const float*)d_in[13];
    const float* ba1    = (const float*)d_in[14];
    const float* Wa2    = (const float*)d_in[15];
    const float* ba2    = (const float*)d_in[16];
    float*       out    = (float*)d_out;

    int* scratch = (int*)d_ws;
    const int have_ws = (ws_size >= 2048) ? 1 : 0;

    if (have_ws) {
        gather_stats_kernel<<<272, 256, 0, stream>>>(
            text, emb, W1, b1, b2, b3, Wa1,
            thr1, leak1, thr2, leak2, scratch);
    }
    snn_final_kernel<<<BATCH, 512, 0, stream>>>(
        text, emb, W1, b1, W2, b2, W3, b3,
        thr1, leak1, thr2, leak2,
        Wa1, ba1, Wa2, ba2,
        scratch, have_ws ? 0 : 1, out);
}